// Round 20
// baseline (386.243 us; speedup 1.0000x reference)
//
#include <hip/hip_runtime.h>
#include <hip/hip_bf16.h>
#include <math.h>

#define D_DIM 1024
#define F_DIM 2816
#define E_NUM 8

#define BM 128
#define BK 64

typedef __attribute__((ext_vector_type(4))) float f32x4;
typedef __attribute__((ext_vector_type(8))) short short8;

__device__ __forceinline__ unsigned short f2bf(float f) {
    unsigned u = __float_as_uint(f);
    u = (u + 0x7FFFu + ((u >> 16) & 1u)) >> 16;
    return (unsigned short)u;
}

__device__ __forceinline__ float bf2f(unsigned short h) {
    return __uint_as_float((unsigned)h << 16);
}

__device__ __forceinline__ float gelu_erf(float z) {
    return 0.5f * z * (1.0f + erff(z * 0.70710678118654752f));
}

// XOR swizzle on LDS READ side; WRITE side via pre-swizzled global source.
__device__ __forceinline__ int swz(int row, int kb) {
    return row * 128 + (kb ^ ((row & 7) << 4));
}

__device__ __forceinline__ uint4 pack8(const unsigned short* h) {
    uint4 r;
    r.x = (unsigned)h[0] | ((unsigned)h[1] << 16);
    r.y = (unsigned)h[2] | ((unsigned)h[3] << 16);
    r.z = (unsigned)h[4] | ((unsigned)h[5] << 16);
    r.w = (unsigned)h[6] | ((unsigned)h[7] << 16);
    return r;
}

__device__ __forceinline__ void gload16(const void* g, void* l) {
    __builtin_amdgcn_global_load_lds(
        (const __attribute__((address_space(1))) unsigned int*)g,
        (__attribute__((address_space(3))) unsigned int*)l,
        16, 0, 0);
}

// ---------------- fused prep: weight transposes (gload_lds + swizzle) + router ----------------
// grid (44, 16, 26). z<8: w1; z<16: v1; z<24: w2 (swapped tile roles);
// z=24,25: router planes.
// Transpose tile: 64x64 fp32 in LDS, UNPADDED. Load via global_load_lds w=16 with
// the source column-block pre-swizzled by b ^ ((row>>3)&7) (uniform per instr);
// read side applies the same involution -> <=2-way banking on both sides.
__global__ __launch_bounds__(256) void fused_prep_kernel(
    const float* __restrict__ w1, unsigned short* __restrict__ w1t,
    const float* __restrict__ v1, unsigned short* __restrict__ v1t,
    const float* __restrict__ w2, unsigned short* __restrict__ w2t,
    const float* __restrict__ x, const float* __restrict__ rw,
    unsigned short* __restrict__ xbf, int* __restrict__ tk_idx,
    float* __restrict__ tk_w, int* __restrict__ counts, int T)
{
    __shared__ __align__(16) float tile[64 * 64];   // 16KB, unpadded
    int z = blockIdx.z;

    if (z >= 3 * E_NUM) {
        // ---- router plane ----
        int bidx = (z - 3 * E_NUM) * (44 * 16) + blockIdx.y * 44 + blockIdx.x;
        if (bidx >= T / 4) return;
        int t = bidx * 4 + (threadIdx.x >> 6);
        int lane = threadIdx.x & 63;
        const float* xr = x + (size_t)t * D_DIM;
        float acc[E_NUM];
#pragma unroll
        for (int e = 0; e < E_NUM; ++e) acc[e] = 0.f;
#pragma unroll
        for (int i = 0; i < D_DIM / 64; ++i) {
            int d = lane + 64 * i;
            float xv = xr[d];
            xbf[(size_t)t * D_DIM + d] = f2bf(xv);
            const float* rp = rw + (size_t)d * E_NUM;
#pragma unroll
            for (int e = 0; e < E_NUM; ++e) acc[e] += xv * rp[e];
        }
#pragma unroll
        for (int e = 0; e < E_NUM; ++e) {
#pragma unroll
            for (int s = 32; s > 0; s >>= 1) acc[e] += __shfl_xor(acc[e], s, 64);
        }
        float mx = acc[0];
#pragma unroll
        for (int e = 1; e < E_NUM; ++e) mx = fmaxf(mx, acc[e]);
        float p[E_NUM], se = 0.f;
#pragma unroll
        for (int e = 0; e < E_NUM; ++e) { p[e] = expf(acc[e] - mx); se += p[e]; }
        float inv = 1.f / se;
        int e1 = 0;
#pragma unroll
        for (int e = 1; e < E_NUM; ++e) if (p[e] > p[e1]) e1 = e;
        int e2 = (e1 == 0) ? 1 : 0;
#pragma unroll
        for (int e = 0; e < E_NUM; ++e) if (e != e1 && p[e] > p[e2]) e2 = e;
        if (lane == 0) {
            tk_idx[2 * t] = e1; tk_idx[2 * t + 1] = e2;
            tk_w[2 * t] = p[e1] * inv; tk_w[2 * t + 1] = p[e2] * inv;
            atomicAdd(&counts[e1], 1);
            atomicAdd(&counts[e2], 1);
        }
        return;
    }

    // ---- transpose planes ----
    int e = z & 7;
    const float* s;
    unsigned short* d;
    int R, C, c0, r0;
    if (z < 2 * E_NUM) {
        s = (z < E_NUM ? w1 : v1);
        d = (z < E_NUM ? w1t : v1t);
        R = D_DIM; C = F_DIM;
        c0 = blockIdx.x * 64;
        r0 = blockIdx.y * 64;
    } else {
        s = w2; d = w2t;
        R = F_DIM; C = D_DIM;
        c0 = blockIdx.y * 64;
        r0 = blockIdx.x * 64;
    }
    s += (size_t)e * D_DIM * F_DIM;
    d += (size_t)e * D_DIM * F_DIM;

    int tid = threadIdx.x;
    int l = tid & 63;
    int w = tid >> 6;        // wave 0..3

    // load: wave w fills rows 16w..16w+15; per q, lane l -> row 16w+4q+(l>>4),
    // physical 16B block (l&15). Source block pre-swizzled by sblk = (row>>3)&7
    // (= 2w + (q>>1), uniform per instruction).
#pragma unroll
    for (int q = 0; q < 4; ++q) {
        int r = 16 * w + 4 * q + (l >> 4);
        int sblk = (r >> 3) & 7;
        const char* g = (const char*)(s + (size_t)(r0 + r) * C + c0) + (((l & 15) ^ sblk) << 4);
        gload16(g, (char*)tile + (w * 4 + q) * 1024);
    }
    __syncthreads();

    // read + convert + store: thread -> output col c, rows rr..rr+7.
    // physical float col = 4*((c>>2) ^ ((row>>3)&7)) + (c&3); row>>3 = idx&7 (const/thread).
#pragma unroll
    for (int i = 0; i < 2; ++i) {
        int idx = tid + 256 * i;
        int c = idx >> 3;
        int rr = (idx & 7) * 8;
        int sp = idx & 7;
        int pcol = ((((c >> 2) ^ sp) << 2) | (c & 3));
        unsigned short h[8];
#pragma unroll
        for (int j = 0; j < 8; ++j)
            h[j] = f2bf(tile[(rr + j) * 64 + pcol]);
        *(uint4*)(d + (size_t)(c0 + c) * R + r0 + rr) = pack8(h);
    }
}

// ---------------- scan: offsets + cursor + tile map ----------------
__global__ void scan_kernel(const int* __restrict__ counts, int* __restrict__ offsets,
                            int* __restrict__ cursor,
                            int* __restrict__ tile_e, int* __restrict__ tile_row,
                            int* __restrict__ n_mt)
{
    if (threadIdx.x != 0) return;
    int off = 0, nt = 0;
    for (int e = 0; e < E_NUM; ++e) {
        offsets[e] = off;
        cursor[e] = off;
        int ne = counts[e];
        int nti = (ne + BM - 1) / BM;
        for (int i = 0; i < nti; ++i) { tile_e[nt] = e; tile_row[nt] = off + i * BM; ++nt; }
        off += ne;
    }
    offsets[E_NUM] = off;
    *n_mt = nt;
}

// ---------------- assign: LDS-aggregated position assignment ----------------
__global__ __launch_bounds__(256) void assign_kernel(
    const int* __restrict__ tk_idx, int* __restrict__ cursor,
    int* __restrict__ pair_token, int* __restrict__ pair_pos, int T)
{
    __shared__ int lcnt[E_NUM];
    __shared__ int base[E_NUM];
    int tid = threadIdx.x;
    if (tid < E_NUM) lcnt[tid] = 0;
    __syncthreads();
    int t = blockIdx.x * 256 + tid;
    int e0 = 0, e1 = 0, o0 = 0, o1 = 0;
    bool valid = (t < T);
    if (valid) {
        e0 = tk_idx[2 * t];
        e1 = tk_idx[2 * t + 1];
        o0 = atomicAdd(&lcnt[e0], 1);
        o1 = atomicAdd(&lcnt[e1], 1);
    }
    __syncthreads();
    if (tid < E_NUM) base[tid] = atomicAdd(&cursor[tid], lcnt[tid]);
    __syncthreads();
    if (valid) {
        int p0 = base[e0] + o0;
        int p1 = base[e1] + o1;
        pair_token[p0] = t;
        pair_pos[2 * t] = p0;
        pair_token[p1] = t;
        pair_pos[2 * t + 1] = p1;
    }
}

// ---------------- grouped GEMM1 + GLU (r11/r14-proven, FROZEN) ----------------
__global__ __launch_bounds__(512) void gemm1_glu_kernel(
    const unsigned short* __restrict__ xbf,
    const unsigned short* __restrict__ w1t, const unsigned short* __restrict__ v1t,
    const int* __restrict__ pair_token, const int* __restrict__ offsets,
    const int* __restrict__ tile_e, const int* __restrict__ tile_row,
    const int* __restrict__ n_mt,
    unsigned short* __restrict__ hbf)
{
    __shared__ __align__(16) unsigned short As[BM * BK];    // 16KB
    __shared__ __align__(16) unsigned short Bs[256 * BK];   // 32KB

    // XCD swizzle (nwg = 72*22 = 1584, divisible by 8)
    int flat = blockIdx.x + gridDim.x * blockIdx.y;
    int nwg = gridDim.x * gridDim.y;
    int L = (flat & 7) * (nwg >> 3) + (flat >> 3);
    int mt = L % gridDim.x;
    int strip = L / gridDim.x;
    if (mt >= *n_mt) return;
    int e = tile_e[mt];
    int row0 = tile_row[mt];
    int end = offsets[e + 1];
    int n0 = strip * 128;   // real F-column base

    int tid = threadIdx.x;
    int lane = tid & 63;
    int wid = tid >> 6;               // 0..7
    int wr = wid >> 2, wc = wid & 3;  // 2M x 4N
    int sub = lane >> 3;
    int srcoff = (((lane & 7) ^ sub) << 4);

    const unsigned short* W0 = w1t + (size_t)e * D_DIM * F_DIM;
    const unsigned short* W1 = v1t + (size_t)e * D_DIM * F_DIM;

    const char* aptr[2];
#pragma unroll
    for (int i = 0; i < 2; ++i) {
        int r = (wid * 2 + i) * 8 + sub;
        int p = row0 + r;
        if (p >= end) p = end - 1;   // garbage rows feed only masked outputs
        aptr[i] = (const char*)(xbf + (size_t)pair_token[p] * D_DIM) + srcoff;
    }
    // B': row r: g=r>>6 (32-col group), s=(r>>5)&1 (0=w1,1=v1), col=n0+g*32+(r&31)
    const char* bptr[4];
#pragma unroll
    for (int i = 0; i < 4; ++i) {
        int r = (wid * 4 + i) * 8 + sub;
        int s = (r >> 5) & 1;
        int col = n0 + (r >> 6) * 32 + (r & 31);
        const unsigned short* base = s ? W1 : W0;
        bptr[i] = (const char*)(base + (size_t)col * D_DIM) + srcoff;
    }

    f32x4 acc[4][4];
#pragma unroll
    for (int m = 0; m < 4; ++m)
#pragma unroll
        for (int n = 0; n < 4; ++n) acc[m][n] = (f32x4){0.f, 0.f, 0.f, 0.f};

    auto STAGE = [&]() {
#pragma unroll
        for (int i = 0; i < 2; ++i) {
            gload16(aptr[i], (char*)As + (wid * 2 + i) * 1024);
            aptr[i] += 128;
        }
#pragma unroll
        for (int i = 0; i < 4; ++i) {
            gload16(bptr[i], (char*)Bs + (wid * 4 + i) * 1024);
            bptr[i] += 128;
        }
    };

    const int NT = D_DIM / BK;   // 16
    for (int kt = 0; kt < NT; ++kt) {
        STAGE();
        __syncthreads();
#pragma unroll
        for (int kk = 0; kk < 2; ++kk) {
            int kb = kk * 64 + (lane >> 4) * 16;
            short8 af[4], bf[4];
#pragma unroll
            for (int m = 0; m < 4; ++m) {
                int row = wr * 64 + m * 16 + (lane & 15);
                af[m] = *(const short8*)((char*)As + swz(row, kb));
            }
#pragma unroll
            for (int n = 0; n < 4; ++n) {
                int rn = wc * 64 + n * 16 + (lane & 15);
                bf[n] = *(const short8*)((char*)Bs + swz(rn, kb));
            }
#pragma unroll
            for (int m = 0; m < 4; ++m)
#pragma unroll
                for (int n = 0; n < 4; ++n)
                    acc[m][n] = __builtin_amdgcn_mfma_f32_16x16x32_bf16(af[m], bf[n], acc[m][n], 0, 0, 0);
        }
        __syncthreads();
    }
    // GLU epilogue: n=0,1 -> w1 (z1); n=2,3 -> v1 (z2), same real column
#pragma unroll
    for (int m = 0; m < 4; ++m) {
#pragma unroll
        for (int j = 0; j < 4; ++j) {
            int rl = wr * 64 + m * 16 + (lane >> 4) * 4 + j;
            int p = row0 + rl;
            if (p < end) {
#pragma unroll
                for (int n = 0; n < 2; ++n) {
                    float z1 = acc[m][n][j];
                    float z2 = acc[m][n + 2][j];
                    int col = n0 + wc * 32 + n * 16 + (lane & 15);
                    hbf[(size_t)p * F_DIM + col] = f2bf(gelu_erf(z1) * z2);
                }
            }
        }
    }
}

// ---------------- grouped GEMM2 (r17-proven): y = h @ w2[e] -> ypair bf16 ----------------
// tile 128x128, 512 thr / 8 waves (2M x 4N), per-wave 64x32, acc[4][2]. LDS 32KB.
__global__ __launch_bounds__(512) void gemm2_kernel(
    const unsigned short* __restrict__ hbf,
    const unsigned short* __restrict__ w2t,
    const int* __restrict__ offsets,
    const int* __restrict__ tile_e, const int* __restrict__ tile_row,
    const int* __restrict__ n_mt,
    unsigned short* __restrict__ ypair)
{
    __shared__ __align__(16) unsigned short As[BM * BK];   // 16KB
    __shared__ __align__(16) unsigned short Bs[128 * BK];  // 16KB

    // XCD swizzle (nwg = 72*8 = 576, divisible by 8)
    int flat = blockIdx.x + gridDim.x * blockIdx.y;
    int nwg = gridDim.x * gridDim.y;
    int L = (flat & 7) * (nwg >> 3) + (flat >> 3);
    int mt = L % gridDim.x;
    int strip = L / gridDim.x;
    if (mt >= *n_mt) return;
    int e = tile_e[mt];
    int row0 = tile_row[mt];
    int end = offsets[e + 1];
    int n0 = strip * 128;

    int tid = threadIdx.x;
    int lane = tid & 63;
    int wid = tid >> 6;               // 0..7
    int wr = wid >> 2, wc = wid & 3;  // 2M x 4N ; per-wave 64(M) x 32(N)
    int sub = lane >> 3;
    int srcoff = (((lane & 7) ^ sub) << 4);

    const unsigned short* W = w2t + (size_t)e * D_DIM * F_DIM;

    const char* aptr[2];
#pragma unroll
    for (int i = 0; i < 2; ++i) {
        int r = (wid * 2 + i) * 8 + sub;
        int p = row0 + r;
        if (p >= end) p = end - 1;
        aptr[i] = (const char*)(hbf + (size_t)p * F_DIM) + srcoff;
    }
    const char* bptr[2];
#pragma unroll
    for (int i = 0; i < 2; ++i) {
        int n = (wid * 2 + i) * 8 + sub;
        bptr[i] = (const char*)(W + (size_t)(n0 + n) * F_DIM) + srcoff;
    }

    f32x4 acc[4][2];
#pragma unroll
    for (int m = 0; m < 4; ++m)
#pragma unroll
        for (int n = 0; n < 2; ++n) acc[m][n] = (f32x4){0.f, 0.f, 0.f, 0.f};

    auto STAGE = [&]() {
#pragma unroll
        for (int i = 0; i < 2; ++i) {
            gload16(aptr[i], (char*)As + (wid * 2 + i) * 1024);
            aptr[i] += 128;
            gload16(bptr[i], (char*)Bs + (wid * 2 + i) * 1024);
            bptr[i] += 128;
        }
    };

    const int NT = F_DIM / BK;   // 44
    for (int kt = 0; kt < NT; ++kt) {
        STAGE();
        __syncthreads();
#pragma unroll
        for (int kk = 0; kk < 2; ++kk) {
            int kb = kk * 64 + (lane >> 4) * 16;
            short8 af[4], bf[2];
#pragma unroll
            for (int m = 0; m < 4; ++m) {
                int row = wr * 64 + m * 16 + (lane & 15);
                af[m] = *(const short8*)((char*)As + swz(row, kb));
            }
#pragma unroll
            for (int n = 0; n < 2; ++n) {
                int rn = wc * 32 + n * 16 + (lane & 15);
                bf[n] = *(const short8*)((char*)Bs + swz(rn, kb));
            }
#pragma unroll
            for (int m = 0; m < 4; ++m)
#pragma unroll
                for (int n = 0; n < 2; ++n)
                    acc[m][n] = __builtin_amdgcn_mfma_f32_16x16x32_bf16(af[m], bf[n], acc[m][n], 0, 0, 0);
        }
        __syncthreads();
    }
#pragma unroll
    for (int m = 0; m < 4; ++m) {
#pragma unroll
        for (int j = 0; j < 4; ++j) {
            int rl = wr * 64 + m * 16 + (lane >> 4) * 4 + j;
            int p = row0 + rl;
            if (p < end) {
#pragma unroll
                for (int n = 0; n < 2; ++n)
                    ypair[(size_t)p * D_DIM + n0 + wc * 32 + n * 16 + (lane & 15)] = f2bf(acc[m][n][j]);
            }
        }
    }
}

// ---------------- combine: out = bias + w0*y[p0] + w1*y[p1] (bf16 y) ----------------
__global__ __launch_bounds__(256) void combine_kernel(
    const unsigned short* __restrict__ ypair, const int* __restrict__ pair_pos,
    const float* __restrict__ tk_w, const float* __restrict__ bias,
    float* __restrict__ out, int total4)
{
    int idx = blockIdx.x * 256 + threadIdx.x;
    if (idx >= total4) return;
    int t = idx >> 8;                    // D/4 = 256 vectors per token
    int d4 = idx & 255;
    int p0 = pair_pos[2 * t], p1 = pair_pos[2 * t + 1];
    float w0 = tk_w[2 * t], w1 = tk_w[2 * t + 1];
    float4 b = ((const float4*)bias)[d4];
    ushort4 u0 = ((const ushort4*)(ypair + (size_t)p0 * D_DIM))[d4];
    ushort4 u1 = ((const ushort4*)(ypair + (size_t)p1 * D_DIM))[d4];
    float4 r;
    r.x = b.x + w0 * bf2f(u0.x) + w1 * bf2f(u1.x);
    r.y = b.y + w0 * bf2f(u0.y) + w1 * bf2f(u1.y);
    r.z = b.z + w0 * bf2f(u0.z) + w1 * bf2f(u1.z);
    r.w = b.w + w0 * bf2f(u0.w) + w1 * bf2f(u1.w);
    ((float4*)out)[idx] = r;
}

__global__ void ws_too_small_kernel(float* out, int n) {
    int i = blockIdx.x * 256 + threadIdx.x;
    if (i < n) out[i] = 12345.0f;
}

extern "C" void kernel_launch(void* const* d_in, const int* in_sizes, int n_in,
                              void* d_out, int out_size, void* d_ws, size_t ws_size,
                              hipStream_t stream) {
    const float* x    = (const float*)d_in[0];
    const float* rw   = (const float*)d_in[1];
    const float* w1   = (const float*)d_in[2];
    const float* v1   = (const float*)d_in[3];
    const float* w2   = (const float*)d_in[4];
    const float* bias = (const float*)d_in[5];
    float* out = (float*)d_out;

    int T = in_sizes[0] / D_DIM;      // 4096
    int P = 2 * T;
    int maxMT = P / BM + E_NUM;       // 72

    char* p = (char*)d_ws;
    char* ws_end = p + ws_size;
    auto alloc = [&](size_t bytes) {
        char* r = p;
        p += (bytes + 255) & ~(size_t)255;
        return r;
    };
    unsigned short* xbf   = (unsigned short*)alloc((size_t)T * D_DIM * 2);
    int*   tk_idx     = (int*)alloc((size_t)T * 2 * 4);
    float* tk_w       = (float*)alloc((size_t)T * 2 * 4);
    int*   counts     = (int*)alloc(E_NUM * 4);
    int*   offsets    = (int*)alloc((E_NUM + 1) * 4);
    int*   cursor     = (int*)alloc(E_NUM * 4);
    int*   tile_e     = (int*)alloc(maxMT * 4);
    int*   tile_row   = (int*)alloc(maxMT * 4);
    int*   n_mt       = (int*)alloc(4);
    int*   pair_token = (int*)alloc((size_t)P * 4);
    int*   pair_pos   = (int*)alloc((size_t)P * 4);
    unsigned short* hbf = (unsigned short*)alloc((size_t)P * F_DIM * 2);
    unsigned short* ypair = (unsigned short*)alloc((size_t)P * D_DIM * 2);
    unsigned short* w1t = (unsigned short*)alloc((size_t)E_NUM * D_DIM * F_DIM * 2);
    unsigned short* v1t = (unsigned short*)alloc((size_t)E_NUM * D_DIM * F_DIM * 2);
    unsigned short* w2t = (unsigned short*)alloc((size_t)E_NUM * D_DIM * F_DIM * 2);

    if (p > ws_end) {
        ws_too_small_kernel<<<(out_size + 255) / 256, 256, 0, stream>>>(out, out_size);
        return;
    }

    hipMemsetAsync(counts, 0, E_NUM * 4, stream);
    // fused: all three weight transposes + router in one launch (z = 0..23 transpose, 24..25 router)
    fused_prep_kernel<<<dim3(F_DIM / 64, D_DIM / 64, 3 * E_NUM + 2), 256, 0, stream>>>(
        w1, w1t, v1, v1t, w2, w2t, x, rw, xbf, tk_idx, tk_w, counts, T);
    scan_kernel<<<1, 64, 0, stream>>>(counts, offsets, cursor, tile_e, tile_row, n_mt);
    assign_kernel<<<(T + 255) / 256, 256, 0, stream>>>(tk_idx, cursor, pair_token, pair_pos, T);
    // gemm1: 22 strips of 128 real F-cols; nwg = 72*22 = 1584 (8 | 1584)
    gemm1_glu_kernel<<<dim3(maxMT, F_DIM / 128), 512, 0, stream>>>(
        xbf, w1t, v1t, pair_token, offsets, tile_e, tile_row, n_mt, hbf);
    // gemm2: 8 strips of 128 D-cols; nwg = 72*8 = 576 (8 | 576)
    gemm2_kernel<<<dim3(maxMT, D_DIM / 128), 512, 0, stream>>>(
        hbf, w2t, offsets, tile_e, tile_row, n_mt, ypair);
    combine_kernel<<<(T * D_DIM / 4 + 255) / 256, 256, 0, stream>>>(
        ypair, pair_pos, tk_w, bias, out, T * D_DIM / 4);
}

// Round 21
// 383.225 us; speedup vs baseline: 1.0079x; 1.0079x over previous
//
#include <hip/hip_runtime.h>
#include <hip/hip_bf16.h>
#include <math.h>

#define D_DIM 1024
#define F_DIM 2816
#define E_NUM 8

#define BM 128
#define BK 64

typedef __attribute__((ext_vector_type(4))) float f32x4;
typedef __attribute__((ext_vector_type(8))) short short8;

__device__ __forceinline__ unsigned short f2bf(float f) {
    unsigned u = __float_as_uint(f);
    u = (u + 0x7FFFu + ((u >> 16) & 1u)) >> 16;
    return (unsigned short)u;
}

__device__ __forceinline__ float bf2f(unsigned short h) {
    return __uint_as_float((unsigned)h << 16);
}

__device__ __forceinline__ float gelu_erf(float z) {
    return 0.5f * z * (1.0f + erff(z * 0.70710678118654752f));
}

// XOR swizzle on LDS READ side; WRITE side via pre-swizzled global source.
__device__ __forceinline__ int swz(int row, int kb) {
    return row * 128 + (kb ^ ((row & 7) << 4));
}

__device__ __forceinline__ uint4 pack8(const unsigned short* h) {
    uint4 r;
    r.x = (unsigned)h[0] | ((unsigned)h[1] << 16);
    r.y = (unsigned)h[2] | ((unsigned)h[3] << 16);
    r.z = (unsigned)h[4] | ((unsigned)h[5] << 16);
    r.w = (unsigned)h[6] | ((unsigned)h[7] << 16);
    return r;
}

__device__ __forceinline__ void gload16(const void* g, void* l) {
    __builtin_amdgcn_global_load_lds(
        (const __attribute__((address_space(1))) unsigned int*)g,
        (__attribute__((address_space(3))) unsigned int*)l,
        16, 0, 0);
}

// ---------------- fused prep: pipelined transposes + router ----------------
// grid (11, 16, 30). z<24: transpose planes, each block = strip of 4 tiles (64x64),
// double-buffered LDS, counted-vmcnt 2-deep pipeline (4 gloads/wave per tile;
// vmcnt(4) -> oldest tile landed; raw s_barrier keeps prefetch in flight).
// z=24..29: router planes (176 blocks each, mask at T/4=1024).
__global__ __launch_bounds__(256) void fused_prep_kernel(
    const float* __restrict__ w1, unsigned short* __restrict__ w1t,
    const float* __restrict__ v1, unsigned short* __restrict__ v1t,
    const float* __restrict__ w2, unsigned short* __restrict__ w2t,
    const float* __restrict__ x, const float* __restrict__ rw,
    unsigned short* __restrict__ xbf, int* __restrict__ tk_idx,
    float* __restrict__ tk_w, int* __restrict__ counts, int T)
{
    __shared__ __align__(16) float tile[2][64 * 64];   // 2 x 16KB
    int z = blockIdx.z;

    if (z >= 3 * E_NUM) {
        // ---- router plane ----
        int bidx = (z - 3 * E_NUM) * (11 * 16) + blockIdx.y * 11 + blockIdx.x;
        if (bidx >= T / 4) return;
        int t = bidx * 4 + (threadIdx.x >> 6);
        int lane = threadIdx.x & 63;
        const float* xr = x + (size_t)t * D_DIM;
        float acc[E_NUM];
#pragma unroll
        for (int e = 0; e < E_NUM; ++e) acc[e] = 0.f;
#pragma unroll
        for (int i = 0; i < D_DIM / 64; ++i) {
            int d = lane + 64 * i;
            float xv = xr[d];
            xbf[(size_t)t * D_DIM + d] = f2bf(xv);
            const float* rp = rw + (size_t)d * E_NUM;
#pragma unroll
            for (int e = 0; e < E_NUM; ++e) acc[e] += xv * rp[e];
        }
#pragma unroll
        for (int e = 0; e < E_NUM; ++e) {
#pragma unroll
            for (int s = 32; s > 0; s >>= 1) acc[e] += __shfl_xor(acc[e], s, 64);
        }
        float mx = acc[0];
#pragma unroll
        for (int e = 1; e < E_NUM; ++e) mx = fmaxf(mx, acc[e]);
        float p[E_NUM], se = 0.f;
#pragma unroll
        for (int e = 0; e < E_NUM; ++e) { p[e] = expf(acc[e] - mx); se += p[e]; }
        float inv = 1.f / se;
        int e1 = 0;
#pragma unroll
        for (int e = 1; e < E_NUM; ++e) if (p[e] > p[e1]) e1 = e;
        int e2 = (e1 == 0) ? 1 : 0;
#pragma unroll
        for (int e = 0; e < E_NUM; ++e) if (e != e1 && p[e] > p[e2]) e2 = e;
        if (lane == 0) {
            tk_idx[2 * t] = e1; tk_idx[2 * t + 1] = e2;
            tk_w[2 * t] = p[e1] * inv; tk_w[2 * t + 1] = p[e2] * inv;
            atomicAdd(&counts[e1], 1);
            atomicAdd(&counts[e2], 1);
        }
        return;
    }

    // ---- transpose planes: strip of 4 tiles ----
    int e = z & 7;
    const float* s;
    unsigned short* d;
    int R, C;
    bool w2mode = (z >= 2 * E_NUM);
    if (!w2mode) {
        s = (z < E_NUM ? w1 : v1);
        d = (z < E_NUM ? w1t : v1t);
        R = D_DIM; C = F_DIM;
    } else {
        s = w2; d = w2t;
        R = F_DIM; C = D_DIM;
    }
    s += (size_t)e * D_DIM * F_DIM;
    d += (size_t)e * D_DIM * F_DIM;

    int tid = threadIdx.x;
    int l = tid & 63;
    int w = tid >> 6;        // wave 0..3

    // per-tile coordinates: tile j at tx = blockIdx.x*4 + j
    auto C0 = [&](int j) { int tx = blockIdx.x * 4 + j;
                           return w2mode ? (int)(blockIdx.y * 64) : tx * 64; };
    auto R0 = [&](int j) { int tx = blockIdx.x * 4 + j;
                           return w2mode ? tx * 64 : (int)(blockIdx.y * 64); };

    // STAGE tile j into buf: per wave exactly 4 gload16 (one per q).
    auto STAGE = [&](int j, int buf) {
        int c0 = C0(j), r0 = R0(j);
#pragma unroll
        for (int q = 0; q < 4; ++q) {
            int r = 16 * w + 4 * q + (l >> 4);
            int sblk = (r >> 3) & 7;
            const char* g = (const char*)(s + (size_t)(r0 + r) * C + c0) + (((l & 15) ^ sblk) << 4);
            gload16(g, (char*)tile[buf] + (w * 4 + q) * 1024);
        }
    };

    STAGE(0, 0);
    STAGE(1, 1);
#pragma unroll 1
    for (int j = 0; j < 4; ++j) {
        int buf = j & 1;
        if (j < 3) asm volatile("s_waitcnt vmcnt(4)" ::: "memory");
        else       asm volatile("s_waitcnt vmcnt(0)" ::: "memory");
        __builtin_amdgcn_s_barrier();          // tile j fully in LDS (all waves waited)
        int c0 = C0(j), r0 = R0(j);
        const float* tb = tile[buf];
#pragma unroll
        for (int i = 0; i < 2; ++i) {
            int idx = tid + 256 * i;
            int c = idx >> 3;
            int rr = (idx & 7) * 8;
            int sp = idx & 7;
            int pcol = ((((c >> 2) ^ sp) << 2) | (c & 3));
            unsigned short h[8];
#pragma unroll
            for (int jj = 0; jj < 8; ++jj)
                h[jj] = f2bf(tb[(rr + jj) * 64 + pcol]);
            *(uint4*)(d + (size_t)(c0 + c) * R + r0 + rr) = pack8(h);
        }
        __builtin_amdgcn_s_barrier();          // all reads of buf done before refill
        if (j + 2 < 4) STAGE(j + 2, buf);
    }
}

// ---------------- scan: offsets + cursor + tile map ----------------
__global__ void scan_kernel(const int* __restrict__ counts, int* __restrict__ offsets,
                            int* __restrict__ cursor,
                            int* __restrict__ tile_e, int* __restrict__ tile_row,
                            int* __restrict__ n_mt)
{
    if (threadIdx.x != 0) return;
    int off = 0, nt = 0;
    for (int e = 0; e < E_NUM; ++e) {
        offsets[e] = off;
        cursor[e] = off;
        int ne = counts[e];
        int nti = (ne + BM - 1) / BM;
        for (int i = 0; i < nti; ++i) { tile_e[nt] = e; tile_row[nt] = off + i * BM; ++nt; }
        off += ne;
    }
    offsets[E_NUM] = off;
    *n_mt = nt;
}

// ---------------- assign: LDS-aggregated position assignment ----------------
__global__ __launch_bounds__(256) void assign_kernel(
    const int* __restrict__ tk_idx, int* __restrict__ cursor,
    int* __restrict__ pair_token, int* __restrict__ pair_pos, int T)
{
    __shared__ int lcnt[E_NUM];
    __shared__ int base[E_NUM];
    int tid = threadIdx.x;
    if (tid < E_NUM) lcnt[tid] = 0;
    __syncthreads();
    int t = blockIdx.x * 256 + tid;
    int e0 = 0, e1 = 0, o0 = 0, o1 = 0;
    bool valid = (t < T);
    if (valid) {
        e0 = tk_idx[2 * t];
        e1 = tk_idx[2 * t + 1];
        o0 = atomicAdd(&lcnt[e0], 1);
        o1 = atomicAdd(&lcnt[e1], 1);
    }
    __syncthreads();
    if (tid < E_NUM) base[tid] = atomicAdd(&cursor[tid], lcnt[tid]);
    __syncthreads();
    if (valid) {
        int p0 = base[e0] + o0;
        int p1 = base[e1] + o1;
        pair_token[p0] = t;
        pair_pos[2 * t] = p0;
        pair_token[p1] = t;
        pair_pos[2 * t + 1] = p1;
    }
}

// ---------------- grouped GEMM1 + GLU (r11/r14-proven, FROZEN) ----------------
__global__ __launch_bounds__(512) void gemm1_glu_kernel(
    const unsigned short* __restrict__ xbf,
    const unsigned short* __restrict__ w1t, const unsigned short* __restrict__ v1t,
    const int* __restrict__ pair_token, const int* __restrict__ offsets,
    const int* __restrict__ tile_e, const int* __restrict__ tile_row,
    const int* __restrict__ n_mt,
    unsigned short* __restrict__ hbf)
{
    __shared__ __align__(16) unsigned short As[BM * BK];    // 16KB
    __shared__ __align__(16) unsigned short Bs[256 * BK];   // 32KB

    // XCD swizzle (nwg = 72*22 = 1584, divisible by 8)
    int flat = blockIdx.x + gridDim.x * blockIdx.y;
    int nwg = gridDim.x * gridDim.y;
    int L = (flat & 7) * (nwg >> 3) + (flat >> 3);
    int mt = L % gridDim.x;
    int strip = L / gridDim.x;
    if (mt >= *n_mt) return;
    int e = tile_e[mt];
    int row0 = tile_row[mt];
    int end = offsets[e + 1];
    int n0 = strip * 128;   // real F-column base

    int tid = threadIdx.x;
    int lane = tid & 63;
    int wid = tid >> 6;               // 0..7
    int wr = wid >> 2, wc = wid & 3;  // 2M x 4N
    int sub = lane >> 3;
    int srcoff = (((lane & 7) ^ sub) << 4);

    const unsigned short* W0 = w1t + (size_t)e * D_DIM * F_DIM;
    const unsigned short* W1 = v1t + (size_t)e * D_DIM * F_DIM;

    const char* aptr[2];
#pragma unroll
    for (int i = 0; i < 2; ++i) {
        int r = (wid * 2 + i) * 8 + sub;
        int p = row0 + r;
        if (p >= end) p = end - 1;   // garbage rows feed only masked outputs
        aptr[i] = (const char*)(xbf + (size_t)pair_token[p] * D_DIM) + srcoff;
    }
    // B': row r: g=r>>6 (32-col group), s=(r>>5)&1 (0=w1,1=v1), col=n0+g*32+(r&31)
    const char* bptr[4];
#pragma unroll
    for (int i = 0; i < 4; ++i) {
        int r = (wid * 4 + i) * 8 + sub;
        int s = (r >> 5) & 1;
        int col = n0 + (r >> 6) * 32 + (r & 31);
        const unsigned short* base = s ? W1 : W0;
        bptr[i] = (const char*)(base + (size_t)col * D_DIM) + srcoff;
    }

    f32x4 acc[4][4];
#pragma unroll
    for (int m = 0; m < 4; ++m)
#pragma unroll
        for (int n = 0; n < 4; ++n) acc[m][n] = (f32x4){0.f, 0.f, 0.f, 0.f};

    auto STAGE = [&]() {
#pragma unroll
        for (int i = 0; i < 2; ++i) {
            gload16(aptr[i], (char*)As + (wid * 2 + i) * 1024);
            aptr[i] += 128;
        }
#pragma unroll
        for (int i = 0; i < 4; ++i) {
            gload16(bptr[i], (char*)Bs + (wid * 4 + i) * 1024);
            bptr[i] += 128;
        }
    };

    const int NT = D_DIM / BK;   // 16
    for (int kt = 0; kt < NT; ++kt) {
        STAGE();
        __syncthreads();
#pragma unroll
        for (int kk = 0; kk < 2; ++kk) {
            int kb = kk * 64 + (lane >> 4) * 16;
            short8 af[4], bf[4];
#pragma unroll
            for (int m = 0; m < 4; ++m) {
                int row = wr * 64 + m * 16 + (lane & 15);
                af[m] = *(const short8*)((char*)As + swz(row, kb));
            }
#pragma unroll
            for (int n = 0; n < 4; ++n) {
                int rn = wc * 64 + n * 16 + (lane & 15);
                bf[n] = *(const short8*)((char*)Bs + swz(rn, kb));
            }
#pragma unroll
            for (int m = 0; m < 4; ++m)
#pragma unroll
                for (int n = 0; n < 4; ++n)
                    acc[m][n] = __builtin_amdgcn_mfma_f32_16x16x32_bf16(af[m], bf[n], acc[m][n], 0, 0, 0);
        }
        __syncthreads();
    }
    // GLU epilogue: n=0,1 -> w1 (z1); n=2,3 -> v1 (z2), same real column
#pragma unroll
    for (int m = 0; m < 4; ++m) {
#pragma unroll
        for (int j = 0; j < 4; ++j) {
            int rl = wr * 64 + m * 16 + (lane >> 4) * 4 + j;
            int p = row0 + rl;
            if (p < end) {
#pragma unroll
                for (int n = 0; n < 2; ++n) {
                    float z1 = acc[m][n][j];
                    float z2 = acc[m][n + 2][j];
                    int col = n0 + wc * 32 + n * 16 + (lane & 15);
                    hbf[(size_t)p * F_DIM + col] = f2bf(gelu_erf(z1) * z2);
                }
            }
        }
    }
}

// ---------------- grouped GEMM2 (r17-proven): y = h @ w2[e] -> ypair bf16 ----------------
// tile 128x128, 512 thr / 8 waves (2M x 4N), per-wave 64x32, acc[4][2]. LDS 32KB.
__global__ __launch_bounds__(512) void gemm2_kernel(
    const unsigned short* __restrict__ hbf,
    const unsigned short* __restrict__ w2t,
    const int* __restrict__ offsets,
    const int* __restrict__ tile_e, const int* __restrict__ tile_row,
    const int* __restrict__ n_mt,
    unsigned short* __restrict__ ypair)
{
    __shared__ __align__(16) unsigned short As[BM * BK];   // 16KB
    __shared__ __align__(16) unsigned short Bs[128 * BK];  // 16KB

    // XCD swizzle (nwg = 72*8 = 576, divisible by 8)
    int flat = blockIdx.x + gridDim.x * blockIdx.y;
    int nwg = gridDim.x * gridDim.y;
    int L = (flat & 7) * (nwg >> 3) + (flat >> 3);
    int mt = L % gridDim.x;
    int strip = L / gridDim.x;
    if (mt >= *n_mt) return;
    int e = tile_e[mt];
    int row0 = tile_row[mt];
    int end = offsets[e + 1];
    int n0 = strip * 128;

    int tid = threadIdx.x;
    int lane = tid & 63;
    int wid = tid >> 6;               // 0..7
    int wr = wid >> 2, wc = wid & 3;  // 2M x 4N ; per-wave 64(M) x 32(N)
    int sub = lane >> 3;
    int srcoff = (((lane & 7) ^ sub) << 4);

    const unsigned short* W = w2t + (size_t)e * D_DIM * F_DIM;

    const char* aptr[2];
#pragma unroll
    for (int i = 0; i < 2; ++i) {
        int r = (wid * 2 + i) * 8 + sub;
        int p = row0 + r;
        if (p >= end) p = end - 1;
        aptr[i] = (const char*)(hbf + (size_t)p * F_DIM) + srcoff;
    }
    const char* bptr[2];
#pragma unroll
    for (int i = 0; i < 2; ++i) {
        int n = (wid * 2 + i) * 8 + sub;
        bptr[i] = (const char*)(W + (size_t)(n0 + n) * F_DIM) + srcoff;
    }

    f32x4 acc[4][2];
#pragma unroll
    for (int m = 0; m < 4; ++m)
#pragma unroll
        for (int n = 0; n < 2; ++n) acc[m][n] = (f32x4){0.f, 0.f, 0.f, 0.f};

    auto STAGE = [&]() {
#pragma unroll
        for (int i = 0; i < 2; ++i) {
            gload16(aptr[i], (char*)As + (wid * 2 + i) * 1024);
            aptr[i] += 128;
            gload16(bptr[i], (char*)Bs + (wid * 2 + i) * 1024);
            bptr[i] += 128;
        }
    };

    const int NT = F_DIM / BK;   // 44
    for (int kt = 0; kt < NT; ++kt) {
        STAGE();
        __syncthreads();
#pragma unroll
        for (int kk = 0; kk < 2; ++kk) {
            int kb = kk * 64 + (lane >> 4) * 16;
            short8 af[4], bf[2];
#pragma unroll
            for (int m = 0; m < 4; ++m) {
                int row = wr * 64 + m * 16 + (lane & 15);
                af[m] = *(const short8*)((char*)As + swz(row, kb));
            }
#pragma unroll
            for (int n = 0; n < 2; ++n) {
                int rn = wc * 32 + n * 16 + (lane & 15);
                bf[n] = *(const short8*)((char*)Bs + swz(rn, kb));
            }
#pragma unroll
            for (int m = 0; m < 4; ++m)
#pragma unroll
                for (int n = 0; n < 2; ++n)
                    acc[m][n] = __builtin_amdgcn_mfma_f32_16x16x32_bf16(af[m], bf[n], acc[m][n], 0, 0, 0);
        }
        __syncthreads();
    }
#pragma unroll
    for (int m = 0; m < 4; ++m) {
#pragma unroll
        for (int j = 0; j < 4; ++j) {
            int rl = wr * 64 + m * 16 + (lane >> 4) * 4 + j;
            int p = row0 + rl;
            if (p < end) {
#pragma unroll
                for (int n = 0; n < 2; ++n)
                    ypair[(size_t)p * D_DIM + n0 + wc * 32 + n * 16 + (lane & 15)] = f2bf(acc[m][n][j]);
            }
        }
    }
}

// ---------------- combine: out = bias + w0*y[p0] + w1*y[p1] (bf16 y) ----------------
__global__ __launch_bounds__(256) void combine_kernel(
    const unsigned short* __restrict__ ypair, const int* __restrict__ pair_pos,
    const float* __restrict__ tk_w, const float* __restrict__ bias,
    float* __restrict__ out, int total4)
{
    int idx = blockIdx.x * 256 + threadIdx.x;
    if (idx >= total4) return;
    int t = idx >> 8;                    // D/4 = 256 vectors per token
    int d4 = idx & 255;
    int p0 = pair_pos[2 * t], p1 = pair_pos[2 * t + 1];
    float w0 = tk_w[2 * t], w1 = tk_w[2 * t + 1];
    float4 b = ((const float4*)bias)[d4];
    ushort4 u0 = ((const ushort4*)(ypair + (size_t)p0 * D_DIM))[d4];
    ushort4 u1 = ((const ushort4*)(ypair + (size_t)p1 * D_DIM))[d4];
    float4 r;
    r.x = b.x + w0 * bf2f(u0.x) + w1 * bf2f(u1.x);
    r.y = b.y + w0 * bf2f(u0.y) + w1 * bf2f(u1.y);
    r.z = b.z + w0 * bf2f(u0.z) + w1 * bf2f(u1.z);
    r.w = b.w + w0 * bf2f(u0.w) + w1 * bf2f(u1.w);
    ((float4*)out)[idx] = r;
}

__global__ void ws_too_small_kernel(float* out, int n) {
    int i = blockIdx.x * 256 + threadIdx.x;
    if (i < n) out[i] = 12345.0f;
}

extern "C" void kernel_launch(void* const* d_in, const int* in_sizes, int n_in,
                              void* d_out, int out_size, void* d_ws, size_t ws_size,
                              hipStream_t stream) {
    const float* x    = (const float*)d_in[0];
    const float* rw   = (const float*)d_in[1];
    const float* w1   = (const float*)d_in[2];
    const float* v1   = (const float*)d_in[3];
    const float* w2   = (const float*)d_in[4];
    const float* bias = (const float*)d_in[5];
    float* out = (float*)d_out;

    int T = in_sizes[0] / D_DIM;      // 4096
    int P = 2 * T;
    int maxMT = P / BM + E_NUM;       // 72

    char* p = (char*)d_ws;
    char* ws_end = p + ws_size;
    auto alloc = [&](size_t bytes) {
        char* r = p;
        p += (bytes + 255) & ~(size_t)255;
        return r;
    };
    unsigned short* xbf   = (unsigned short*)alloc((size_t)T * D_DIM * 2);
    int*   tk_idx     = (int*)alloc((size_t)T * 2 * 4);
    float* tk_w       = (float*)alloc((size_t)T * 2 * 4);
    int*   counts     = (int*)alloc(E_NUM * 4);
    int*   offsets    = (int*)alloc((E_NUM + 1) * 4);
    int*   cursor     = (int*)alloc(E_NUM * 4);
    int*   tile_e     = (int*)alloc(maxMT * 4);
    int*   tile_row   = (int*)alloc(maxMT * 4);
    int*   n_mt       = (int*)alloc(4);
    int*   pair_token = (int*)alloc((size_t)P * 4);
    int*   pair_pos   = (int*)alloc((size_t)P * 4);
    unsigned short* hbf = (unsigned short*)alloc((size_t)P * F_DIM * 2);
    unsigned short* ypair = (unsigned short*)alloc((size_t)P * D_DIM * 2);
    unsigned short* w1t = (unsigned short*)alloc((size_t)E_NUM * D_DIM * F_DIM * 2);
    unsigned short* v1t = (unsigned short*)alloc((size_t)E_NUM * D_DIM * F_DIM * 2);
    unsigned short* w2t = (unsigned short*)alloc((size_t)E_NUM * D_DIM * F_DIM * 2);

    if (p > ws_end) {
        ws_too_small_kernel<<<(out_size + 255) / 256, 256, 0, stream>>>(out, out_size);
        return;
    }

    hipMemsetAsync(counts, 0, E_NUM * 4, stream);
    // fused: pipelined transposes (strips of 4 tiles) + router (z=24..29)
    fused_prep_kernel<<<dim3(F_DIM / 256, D_DIM / 64, 3 * E_NUM + 6), 256, 0, stream>>>(
        w1, w1t, v1, v1t, w2, w2t, x, rw, xbf, tk_idx, tk_w, counts, T);
    scan_kernel<<<1, 64, 0, stream>>>(counts, offsets, cursor, tile_e, tile_row, n_mt);
    assign_kernel<<<(T + 255) / 256, 256, 0, stream>>>(tk_idx, cursor, pair_token, pair_pos, T);
    // gemm1: 22 strips of 128 real F-cols; nwg = 72*22 = 1584 (8 | 1584)
    gemm1_glu_kernel<<<dim3(maxMT, F_DIM / 128), 512, 0, stream>>>(
        xbf, w1t, v1t, pair_token, offsets, tile_e, tile_row, n_mt, hbf);
    // gemm2: 8 strips of 128 D-cols; nwg = 72*8 = 576 (8 | 576)
    gemm2_kernel<<<dim3(maxMT, D_DIM / 128), 512, 0, stream>>>(
        hbf, w2t, offsets, tile_e, tile_row, n_mt, ypair);
    combine_kernel<<<(T * D_DIM / 4 + 255) / 256, 256, 0, stream>>>(
        ypair, pair_pos, tk_w, bias, out, T * D_DIM / 4);
}